// Round 1
// baseline (330.070 us; speedup 1.0000x reference)
//
#include <hip/hip_runtime.h>
#include <hip/hip_bf16.h>

// SlotAttention on MI355X.
// B=64, N=4096, Din=D=64, S=7, H=128, 3 iterations.
// Strategy:
//  - prep: fold LN-gamma into Wk/Wv (G = diag(g)W), precompute colsums; store G^T bf16.
//  - proj: bf16 MFMA x@Gk, x@Gv with exact f32 LN stats applied in epilogue; k,v stored bf16 (32MB each).
//  - per iter: slots_pre (LN+q, zero U/Z) -> attn streaming pass (U=sum a*v, Z=sum a, atomics)
//              -> slots_post (updates=U/Z, GRU, LN, MLP residual).

#define NB 64
#define NN 4096
#define NS 7
#define LN_EPS 1e-3f
#define EPS_ATTN 1e-8f

typedef __attribute__((ext_vector_type(8))) __bf16 bf16x8;
typedef __attribute__((ext_vector_type(4))) float f32x4;

__device__ __forceinline__ unsigned short f2bf(float f) {
    unsigned int x = __float_as_uint(f);
    x += 0x7FFFu + ((x >> 16) & 1u);
    return (unsigned short)(x >> 16);
}

// ---------------- prep: G^T = (g (.) W)^T as bf16, colsums cg, cb ----------------
__global__ void prep_kernel(const float* __restrict__ Wk, const float* __restrict__ Wv,
                            const float* __restrict__ g, const float* __restrict__ bb,
                            unsigned short* __restrict__ GkT, unsigned short* __restrict__ GvT,
                            float* __restrict__ cgk, float* __restrict__ cbk,
                            float* __restrict__ cgv, float* __restrict__ cbv) {
    int t = threadIdx.x;          // 0..127
    int mat = t >> 6, j = t & 63;
    const float* W = mat ? Wv : Wk;
    unsigned short* GT = mat ? GvT : GkT;
    float* cg = mat ? cgv : cgk;
    float* cb = mat ? cbv : cbk;
    float sg = 0.f, sb = 0.f;
    for (int d = 0; d < 64; ++d) {
        float w = W[d * 64 + j];
        float gv = g[d], bv = bb[d];
        sg += gv * w;
        sb += bv * w;
        GT[j * 64 + d] = f2bf(gv * w);
    }
    cg[j] = sg; cb[j] = sb;
}

// ---------------- init slots ----------------
__global__ void init_slots_kernel(const float* __restrict__ noise, const float* __restrict__ mu,
                                  const float* __restrict__ lsig, float* __restrict__ slots) {
    int idx = blockIdx.x * 256 + threadIdx.x;
    if (idx < NB * NS * 64) {
        int d = idx & 63;
        slots[idx] = mu[d] + expf(lsig[d]) * noise[idx];
    }
}

// ---------------- proj: k = LN(x)@Wk, v = LN(x)@Wv via bf16 MFMA ----------------
__global__ __launch_bounds__(256) void proj_kernel(
        const float* __restrict__ x, const unsigned short* __restrict__ GkT,
        const unsigned short* __restrict__ GvT,
        const float* __restrict__ cgk, const float* __restrict__ cbk,
        const float* __restrict__ cgv, const float* __restrict__ cbv,
        unsigned short* __restrict__ kout, unsigned short* __restrict__ vout) {
    __shared__ float xs[64][65];            // f32 tile for exact stats (+1 pad)
    __shared__ unsigned short xb[64][72];   // bf16 tile for MFMA A frags (+16B pad)
    __shared__ float mstat[64], istat[64];
    int t = threadIdx.x;
    long r0 = (long)blockIdx.x * 64;
#pragma unroll
    for (int c = 0; c < 4; ++c) {
        int flat = c * 1024 + t * 4;
        int row = flat >> 6, col = flat & 63;
        const float4 f = *(const float4*)(x + r0 * 64 + flat);
        xs[row][col] = f.x; xs[row][col + 1] = f.y; xs[row][col + 2] = f.z; xs[row][col + 3] = f.w;
        xb[row][col]     = f2bf(f.x);
        xb[row][col + 1] = f2bf(f.y);
        xb[row][col + 2] = f2bf(f.z);
        xb[row][col + 3] = f2bf(f.w);
    }
    __syncthreads();
    {   // row stats: 4 threads per row, 16 elems each, xor-reduce over 4 lanes
        int row = t >> 2, p = t & 3;
        float s1 = 0.f, s2 = 0.f;
#pragma unroll
        for (int i = 0; i < 16; ++i) {
            float v = xs[row][p * 16 + i];
            s1 += v; s2 += v * v;
        }
        s1 += __shfl_xor(s1, 1); s2 += __shfl_xor(s2, 1);
        s1 += __shfl_xor(s1, 2); s2 += __shfl_xor(s2, 2);
        float m = s1 * (1.f / 64.f);
        float var = s2 * (1.f / 64.f) - m * m;
        float inv = rsqrtf(var + LN_EPS);
        if (p == 0) { mstat[row] = m; istat[row] = inv; }
    }
    __syncthreads();
    int w = t >> 6, lane = t & 63;
    int arow = w * 16 + (lane & 15);
    int ak = (lane >> 4) * 8;
    bf16x8 a0 = *(const bf16x8*)(&xb[arow][ak]);
    bf16x8 a1 = *(const bf16x8*)(&xb[arow][32 + ak]);
    f32x4 acck[4], accv[4];
#pragma unroll
    for (int nt = 0; nt < 4; ++nt) {
        acck[nt] = (f32x4){0.f, 0.f, 0.f, 0.f};
        accv[nt] = (f32x4){0.f, 0.f, 0.f, 0.f};
    }
#pragma unroll
    for (int nt = 0; nt < 4; ++nt) {
        int col = nt * 16 + (lane & 15);
        bf16x8 bk0 = *(const bf16x8*)(GkT + col * 64 + ak);
        bf16x8 bk1 = *(const bf16x8*)(GkT + col * 64 + 32 + ak);
        bf16x8 bv0 = *(const bf16x8*)(GvT + col * 64 + ak);
        bf16x8 bv1 = *(const bf16x8*)(GvT + col * 64 + 32 + ak);
        acck[nt] = __builtin_amdgcn_mfma_f32_16x16x32_bf16(a0, bk0, acck[nt], 0, 0, 0);
        acck[nt] = __builtin_amdgcn_mfma_f32_16x16x32_bf16(a1, bk1, acck[nt], 0, 0, 0);
        accv[nt] = __builtin_amdgcn_mfma_f32_16x16x32_bf16(a0, bv0, accv[nt], 0, 0, 0);
        accv[nt] = __builtin_amdgcn_mfma_f32_16x16x32_bf16(a1, bv1, accv[nt], 0, 0, 0);
    }
#pragma unroll
    for (int nt = 0; nt < 4; ++nt) {
        int j = nt * 16 + (lane & 15);
        float cgkj = cgk[j], cbkj = cbk[j], cgvj = cgv[j], cbvj = cbv[j];
#pragma unroll
        for (int r = 0; r < 4; ++r) {
            int row = w * 16 + (lane >> 4) * 4 + r;
            float m = mstat[row], inv = istat[row];
            long gro = (r0 + row) * 64 + j;
            kout[gro] = f2bf(inv * (acck[nt][r] - m * cgkj) + cbkj);
            vout[gro] = f2bf(inv * (accv[nt][r] - m * cgvj) + cbvj);
        }
    }
}

// ---------------- slots_pre: q = LN(slots)@Wq*scale, zero U,Z ----------------
__global__ __launch_bounds__(64) void slots_pre_kernel(
        const float* __restrict__ slots, const float* __restrict__ Wq,
        const float* __restrict__ lg, const float* __restrict__ lb,
        float* __restrict__ q, float* __restrict__ U, float* __restrict__ Z) {
    __shared__ float sn[NS][64];
    int b = blockIdx.x, d = threadIdx.x;
#pragma unroll
    for (int s = 0; s < NS; ++s) {
        float xv = slots[(b * NS + s) * 64 + d];
        float s1 = xv, s2 = xv * xv;
#pragma unroll
        for (int off = 1; off < 64; off <<= 1) {
            s1 += __shfl_xor(s1, off);
            s2 += __shfl_xor(s2, off);
        }
        float m = s1 * (1.f / 64.f);
        float var = s2 * (1.f / 64.f) - m * m;
        float inv = rsqrtf(var + LN_EPS);
        sn[s][d] = (xv - m) * inv * lg[d] + lb[d];
    }
    __syncthreads();
#pragma unroll
    for (int s = 0; s < NS; ++s) {
        float acc = 0.f;
        for (int i = 0; i < 64; ++i) acc += sn[s][i] * Wq[i * 64 + d];
        q[(b * NS + s) * 64 + d] = acc * 0.125f;
    }
    for (int idx = d; idx < NS * 64; idx += 64) U[b * NS * 64 + idx] = 0.f;
    if (d < NS) Z[b * NS + d] = 0.f;
}

// ---------------- attn: one streaming pass over k,v per iteration ----------------
__global__ __launch_bounds__(256) void attn_kernel(
        const unsigned short* __restrict__ kp, const unsigned short* __restrict__ vp,
        const float* __restrict__ q, float* __restrict__ U, float* __restrict__ Z) {
    __shared__ float smem[9312];
    float* kt = smem;            // [64][65]
    float* vt = smem + 4160;     // [64][65]
    float* qs = smem + 8320;     // [7][64]
    float* al = smem + 8768;     // [64][8]
    int t = threadIdx.x;
    int b = blockIdx.x >> 4, blk = blockIdx.x & 15;
    for (int i = t; i < NS * 64; i += 256) qs[i] = q[b * NS * 64 + i];
    float uacc[NS], zacc[NS];
#pragma unroll
    for (int s = 0; s < NS; ++s) { uacc[s] = 0.f; zacc[s] = 0.f; }
    int lane = t & 63, w = t >> 6;
    __syncthreads();
    for (int c = 0; c < 4; ++c) {
        long base = ((long)b * NN + (blk * 4 + c) * 64) * 64;
#pragma unroll
        for (int c2 = 0; c2 < 2; ++c2) {
            int flat = c2 * 2048 + t * 8;
            int row = flat >> 6, col = flat & 63;
            uint4 rk = *(const uint4*)(kp + base + flat);
            uint4 rv = *(const uint4*)(vp + base + flat);
            float* kd = kt + row * 65 + col;
            float* vd = vt + row * 65 + col;
            unsigned int ku[4] = {rk.x, rk.y, rk.z, rk.w};
            unsigned int vu[4] = {rv.x, rv.y, rv.z, rv.w};
#pragma unroll
            for (int e = 0; e < 4; ++e) {
                kd[2 * e]     = __uint_as_float(ku[e] << 16);
                kd[2 * e + 1] = __uint_as_float(ku[e] & 0xFFFF0000u);
                vd[2 * e]     = __uint_as_float(vu[e] << 16);
                vd[2 * e + 1] = __uint_as_float(vu[e] & 0xFFFF0000u);
            }
        }
        __syncthreads();
        {   // phase 1: logits + softmax; 4 threads per row
            int row = t >> 2, p = t & 3;
            float lgt[NS];
#pragma unroll
            for (int s = 0; s < NS; ++s) lgt[s] = 0.f;
            const float* krow = kt + row * 65 + p * 16;
#pragma unroll
            for (int i = 0; i < 16; ++i) {
                float kv = krow[i];
#pragma unroll
                for (int s = 0; s < NS; ++s) lgt[s] += kv * qs[s * 64 + p * 16 + i];
            }
#pragma unroll
            for (int s = 0; s < NS; ++s) {
                lgt[s] += __shfl_xor(lgt[s], 1);
                lgt[s] += __shfl_xor(lgt[s], 2);
            }
            float mx = lgt[0];
#pragma unroll
            for (int s = 1; s < NS; ++s) mx = fmaxf(mx, lgt[s]);
            float se = 0.f, ev[NS];
#pragma unroll
            for (int s = 0; s < NS; ++s) { ev[s] = __expf(lgt[s] - mx); se += ev[s]; }
            float rcp = 1.f / se;
            float av[NS];
#pragma unroll
            for (int s = 0; s < NS; ++s) av[s] = ev[s] * rcp + EPS_ATTN;
            if (p == 0) {
#pragma unroll
                for (int s = 0; s < NS; ++s) al[row * 8 + s] = av[s];
            }
            // Z partial: full-wave butterfly counts each row 4x -> *0.25
#pragma unroll
            for (int s = 0; s < NS; ++s) {
                float z0 = av[s];
                z0 += __shfl_xor(z0, 1);  z0 += __shfl_xor(z0, 2);
                z0 += __shfl_xor(z0, 4);  z0 += __shfl_xor(z0, 8);
                z0 += __shfl_xor(z0, 16); z0 += __shfl_xor(z0, 32);
                zacc[s] += 0.25f * z0;
            }
        }
        __syncthreads();
        {   // phase 2: U accumulation, wave w handles rows 16w..16w+15, lane = dim
#pragma unroll
            for (int n = 0; n < 16; ++n) {
                int rr = w * 16 + n;
                float vv = vt[rr * 65 + lane];
                const float* ar = al + rr * 8;
#pragma unroll
                for (int s = 0; s < NS; ++s) uacc[s] += ar[s] * vv;
            }
        }
        __syncthreads();
    }
    // block reduce (reuse kt region) + atomics
#pragma unroll
    for (int s = 0; s < NS; ++s) smem[(w * NS + s) * 64 + lane] = uacc[s];
    if (lane == 0) {
#pragma unroll
        for (int s = 0; s < NS; ++s) smem[1792 + w * NS + s] = zacc[s];
    }
    __syncthreads();
    for (int idx = t; idx < NS * 64; idx += 256) {
        float tot = smem[idx] + smem[448 + idx] + smem[896 + idx] + smem[1344 + idx];
        atomicAdd(&U[b * NS * 64 + idx], tot);
    }
    if (t < NS) {
        float tot = smem[1792 + t] + smem[1799 + t] + smem[1806 + t] + smem[1813 + t];
        atomicAdd(&Z[b * NS + t], tot);
    }
}

// ---------------- slots_post: updates=U/Z, GRU, LN, MLP residual ----------------
__global__ __launch_bounds__(64) void slots_post_kernel(
        float* __restrict__ slots, const float* __restrict__ U, const float* __restrict__ Z,
        const float* __restrict__ gW, const float* __restrict__ gU, const float* __restrict__ gb,
        const float* __restrict__ lmg, const float* __restrict__ lmb,
        const float* __restrict__ W1, const float* __restrict__ b1,
        const float* __restrict__ W2, const float* __restrict__ b2,
        float* __restrict__ outp) {
    __shared__ float up[64], hp[64], mm[64], hl[128];
    int bs = blockIdx.x;    // b*7+s
    int d = threadIdx.x;
    float zsum = Z[bs];
    up[d] = U[bs * 64 + d] / zsum;
    hp[d] = slots[bs * 64 + d];
    __syncthreads();
    float xz = gb[d], xr = gb[64 + d], xh = gb[128 + d];
    float hz = gb[192 + d], hr = gb[256 + d], hh = gb[320 + d];
    for (int i = 0; i < 64; ++i) {
        float u = up[i], h0 = hp[i];
        xz += u * gW[i * 192 + d];
        xr += u * gW[i * 192 + 64 + d];
        xh += u * gW[i * 192 + 128 + d];
        hz += h0 * gU[i * 192 + d];
        hr += h0 * gU[i * 192 + 64 + d];
        hh += h0 * gU[i * 192 + 128 + d];
    }
    float zz = 1.f / (1.f + expf(-(xz + hz)));
    float rr = 1.f / (1.f + expf(-(xr + hr)));
    float hc = tanhf(xh + rr * hh);
    float hnew = zz * hp[d] + (1.f - zz) * hc;
    float s1 = hnew, s2 = hnew * hnew;
#pragma unroll
    for (int off = 1; off < 64; off <<= 1) { s1 += __shfl_xor(s1, off); s2 += __shfl_xor(s2, off); }
    float m = s1 * (1.f / 64.f);
    float var = s2 * (1.f / 64.f) - m * m;
    float inv = rsqrtf(var + LN_EPS);
    mm[d] = (hnew - m) * inv * lmg[d] + lmb[d];
    __syncthreads();
    float h1 = b1[d], h2 = b1[64 + d];
    for (int i = 0; i < 64; ++i) {
        float mv = mm[i];
        h1 += mv * W1[i * 128 + d];
        h2 += mv * W1[i * 128 + 64 + d];
    }
    hl[d] = fmaxf(h1, 0.f); hl[64 + d] = fmaxf(h2, 0.f);
    __syncthreads();
    float o = hnew + b2[d];
    for (int j = 0; j < 128; ++j) o += hl[j] * W2[j * 64 + d];
    slots[bs * 64 + d] = o;
    if (outp) outp[bs * 64 + d] = o;
}

extern "C" void kernel_launch(void* const* d_in, const int* in_sizes, int n_in,
                              void* d_out, int out_size, void* d_ws, size_t ws_size,
                              hipStream_t stream) {
    const float* inputs  = (const float*)d_in[0];
    const float* noise   = (const float*)d_in[1];
    const float* ln_in_g = (const float*)d_in[2];
    const float* ln_in_b = (const float*)d_in[3];
    const float* ln_s_g  = (const float*)d_in[4];
    const float* ln_s_b  = (const float*)d_in[5];
    const float* ln_m_g  = (const float*)d_in[6];
    const float* ln_m_b  = (const float*)d_in[7];
    const float* Wq      = (const float*)d_in[8];
    const float* Wk      = (const float*)d_in[9];
    const float* Wv      = (const float*)d_in[10];
    const float* mu      = (const float*)d_in[11];
    const float* lsig    = (const float*)d_in[12];
    const float* gW      = (const float*)d_in[13];
    const float* gU      = (const float*)d_in[14];
    const float* gb      = (const float*)d_in[15];
    const float* W1      = (const float*)d_in[16];
    const float* b1      = (const float*)d_in[17];
    const float* W2      = (const float*)d_in[18];
    const float* b2      = (const float*)d_in[19];

    char* ws = (char*)d_ws;
    unsigned short* kbuf = (unsigned short*)ws;                        // 32MB
    unsigned short* vbuf = (unsigned short*)(ws + 33554432);           // 32MB
    float* slots = (float*)(ws + 67108864);                            // 448KB region for smalls
    float* qbuf  = (float*)(ws + 67108864 + 114688);
    float* Ubuf  = (float*)(ws + 67108864 + 2 * 114688);
    float* Zbuf  = (float*)(ws + 67108864 + 3 * 114688);
    unsigned short* GkT = (unsigned short*)(ws + 67108864 + 3 * 114688 + 4096);
    unsigned short* GvT = GkT + 4096;
    float* cgk = (float*)(GvT + 4096);
    float* cbk = cgk + 64;
    float* cgv = cbk + 64;
    float* cbv = cgv + 64;

    prep_kernel<<<1, 128, 0, stream>>>(Wk, Wv, ln_in_g, ln_in_b, GkT, GvT, cgk, cbk, cgv, cbv);
    init_slots_kernel<<<112, 256, 0, stream>>>(noise, mu, lsig, slots);
    proj_kernel<<<4096, 256, 0, stream>>>(inputs, GkT, GvT, cgk, cbk, cgv, cbv, kbuf, vbuf);
    for (int it = 0; it < 3; ++it) {
        slots_pre_kernel<<<64, 64, 0, stream>>>(slots, Wq, ln_s_g, ln_s_b, qbuf, Ubuf, Zbuf);
        attn_kernel<<<1024, 256, 0, stream>>>(kbuf, vbuf, qbuf, Ubuf, Zbuf);
        slots_post_kernel<<<448, 64, 0, stream>>>(slots, Ubuf, Zbuf, gW, gU, gb,
                                                  ln_m_g, ln_m_b, W1, b1, W2, b2,
                                                  (it == 2) ? (float*)d_out : nullptr);
    }
}